// Round 7
// baseline (28.894 us; speedup 1.0000x reference)
//
#include <hip/hip_runtime.h>

// PlaceFields: out = sum_{n,p} (scales[n]*exp(-0.5*q(n,p)) - real[n,p])^2
// N=512, P=256*256. Memory-bound on `real` (134 MB f32, ~half L3-resident).
//
// R7: R6 + prefetch depth 2 (3-buffer rotation, 4 float4 real-loads in flight
// per lane). Main kernel is latency-bound (5.6 TB/s effective vs ~11 TB/s
// combined HBM+L3 delivery): double the in-flight bytes.
// Two-kernel structure retained (fusion regressed in R4/R5).

#define NPIX   65536
#define CPX    2048
#define GN     8
#define BLOCK  256
#define PPT    (CPX / BLOCK)   // 8 pixels per thread

__global__ __launch_bounds__(BLOCK) void pf_main(
    const float* __restrict__ coords,      // (P,2)
    const float* __restrict__ real,        // (N,P)
    const float* __restrict__ means,       // (N,2)
    const float* __restrict__ cid,         // (N,2)
    const float* __restrict__ cod,         // (N,1)
    const float* __restrict__ scales,      // (N,1)
    float* __restrict__ partial)           // (gridDim.x)
{
    const int nchunks = NPIX / CPX;                 // 32
    const int n0 = (blockIdx.x / nchunks) * GN;
    const int p0 = (blockIdx.x % nchunks) * CPX;
    const int tid = threadIdx.x;
    const int pb  = p0 + tid * PPT;

    // 8 pixels of coords -> registers, once per block (cached loads).
    const float4 c0 = *reinterpret_cast<const float4*>(coords + 2 * pb);
    const float4 c1 = *reinterpret_cast<const float4*>(coords + 2 * pb + 4);
    const float4 c2 = *reinterpret_cast<const float4*>(coords + 2 * pb + 8);
    const float4 c3 = *reinterpret_cast<const float4*>(coords + 2 * pb + 12);

    float px[PPT]  = {c0.x, c0.z, c1.x, c1.z, c2.x, c2.z, c3.x, c3.z};
    float py[PPT]  = {c0.y, c0.w, c1.y, c1.w, c2.y, c2.w, c3.y, c3.w};
    float pxx[PPT], pxy[PPT], pyy[PPT];
    #pragma unroll
    for (int j = 0; j < PPT; ++j) {
        pxx[j] = px[j] * px[j];
        pxy[j] = px[j] * py[j];
        pyy[j] = py[j] * py[j];
    }

    const float K = -0.72134752044448169f;   // -0.5 / ln(2)

    const float* __restrict__ rpb = real + (size_t)n0 * NPIX + pb;

    // prefetch gaussians 0 and 1 (plain cached loads); 3-slot rotation
    float4 r0 = *reinterpret_cast<const float4*>(rpb);
    float4 r1 = *reinterpret_cast<const float4*>(rpb + 4);
    float4 t0 = *reinterpret_cast<const float4*>(rpb + NPIX);
    float4 t1 = *reinterpret_cast<const float4*>(rpb + NPIX + 4);

    float acc = 0.0f;
    #pragma unroll
    for (int g = 0; g < GN; ++g) {
        const int n = n0 + g;
        const float mx = means[2 * n];
        const float my = means[2 * n + 1];
        const float a  = cid[2 * n];
        const float cc = cid[2 * n + 1];
        const float bb = cod[n];
        const float s  = scales[n];

        const float A  = K * a;
        const float Bh = K * bb;
        const float C  = K * cc;
        const float cB = 2.0f * Bh;
        const float cE = -2.0f * (A * mx + Bh * my);
        const float cF = -2.0f * (Bh * mx + C * my);
        const float cG = A * mx * mx + cB * mx * my + C * my * my
                       + __builtin_amdgcn_logf(s);   // v_log_f32 = log2

        // issue loads for gaussian g+2 before computing gaussian g
        float4 s0, s1;
        if (g + 2 < GN) {
            const float* rn = rpb + (size_t)(g + 2) * NPIX;
            s0 = *reinterpret_cast<const float4*>(rn);
            s1 = *reinterpret_cast<const float4*>(rn + 4);
        }

        const float rr[PPT] = {r0.x, r0.y, r0.z, r0.w, r1.x, r1.y, r1.z, r1.w};

        #pragma unroll
        for (int j = 0; j < PPT; ++j) {
            const float t = fmaf(A,  pxx[j],
                            fmaf(cB, pxy[j],
                            fmaf(C,  pyy[j],
                            fmaf(cE, px[j],
                            fmaf(cF, py[j], cG)))));
            const float pred = __builtin_amdgcn_exp2f(t);
            const float d = pred - rr[j];
            acc = fmaf(d, d, acc);
        }

        r0 = t0; r1 = t1;
        t0 = s0; t1 = s1;
    }

    // wave reduce (64 lanes) then cross-wave via LDS
    #pragma unroll
    for (int off = 32; off > 0; off >>= 1)
        acc += __shfl_down(acc, off, 64);

    __shared__ float wsum[BLOCK / 64];
    const int lane = tid & 63;
    const int wid  = tid >> 6;
    if (lane == 0) wsum[wid] = acc;
    __syncthreads();
    if (tid == 0)
        partial[blockIdx.x] = wsum[0] + wsum[1] + wsum[2] + wsum[3];
}

__global__ __launch_bounds__(BLOCK) void pf_reduce(
    const float* __restrict__ partial, int n, float* __restrict__ out)
{
    float acc = 0.0f;
    for (int i = threadIdx.x; i < n; i += BLOCK) acc += partial[i];
    #pragma unroll
    for (int off = 32; off > 0; off >>= 1)
        acc += __shfl_down(acc, off, 64);
    __shared__ float wsum[BLOCK / 64];
    const int lane = threadIdx.x & 63;
    const int wid  = threadIdx.x >> 6;
    if (lane == 0) wsum[wid] = acc;
    __syncthreads();
    if (threadIdx.x == 0) out[0] = wsum[0] + wsum[1] + wsum[2] + wsum[3];
}

extern "C" void kernel_launch(void* const* d_in, const int* in_sizes, int n_in,
                              void* d_out, int out_size, void* d_ws, size_t ws_size,
                              hipStream_t stream) {
    const float* coords = (const float*)d_in[0];
    const float* real   = (const float*)d_in[1];
    const float* means  = (const float*)d_in[2];
    const float* cid    = (const float*)d_in[3];
    const float* cod    = (const float*)d_in[4];
    const float* scales = (const float*)d_in[5];
    float* out = (float*)d_out;

    const int N = in_sizes[2] / 2;                    // 512
    const int nblocks = (N / GN) * (NPIX / CPX);      // 64 * 32 = 2048
    float* partial = (float*)d_ws;                    // 8 KB

    pf_main<<<dim3(nblocks), dim3(BLOCK), 0, stream>>>(coords, real, means, cid,
                                                       cod, scales, partial);
    pf_reduce<<<dim3(1), dim3(BLOCK), 0, stream>>>(partial, nblocks, out);
}